// Round 4
// baseline (287.910 us; speedup 1.0000x reference)
//
#include <hip/hip_runtime.h>

// Problem constants (match reference)
#define BV    8
#define CV    16
#define NXV   512
#define NYV   512
#define NV    16384
#define NRES  90
#define NHV   5
#define TPB   256
#define CPERT 4                     // channels per thread in gather

#define NPTS  (BV * NV)             // 131072 points
#define TSH   3                     // 8x8-pixel tiles
#define TDIM  (NXV >> TSH)          // 64 tiles per axis
#define NBUCKB (TDIM * TDIM)        // 4096 buckets per batch
#define NBUCK  (BV * NBUCKB)        // 32768 buckets total
#define SCANT 1024
#define SPT   (NBUCK / SCANT)       // 32 elements per scan thread

#if __has_builtin(__builtin_amdgcn_exp2f)
#define EXP2 __builtin_amdgcn_exp2f
#else
#define EXP2 exp2f
#endif

// ---------------- kernel Z: zero bucket counts ----------------
__global__ void zero_counts_kernel(int* __restrict__ counts) {
    int i = blockIdx.x * blockDim.x + threadIdx.x;
    if (i < NBUCK) counts[i] = 0;
}

__device__ __forceinline__ int bucket_key(float rpx, float rpy, int i) {
    const unsigned tx = ((unsigned)(int)rpx) >> TSH;   // 0..63
    const unsigned ty = ((unsigned)(int)rpy) >> TSH;
    unsigned m = 0;
    #pragma unroll
    for (int k = 0; k < 6; ++k)
        m |= (((tx >> k) & 1u) << (2 * k)) | (((ty >> k) & 1u) << (2 * k + 1));
    return (i >> 14) * NBUCKB + (int)m;                // b*4096 + morton
}

// ---------------- kernel A: histogram ----------------
__global__ __launch_bounds__(TPB) void bucket_count_kernel(
    const float* __restrict__ coords, int* __restrict__ counts)
{
    const int i = blockIdx.x * TPB + threadIdx.x;   // i = b*NV + n
    const float2 cd = *(const float2*)(coords + (size_t)i * 2);
    const float rpx = rintf(cd.y * (float)(NXV - 1));
    const float rpy = rintf(cd.x * (float)(NYV - 1));
    atomicAdd(&counts[bucket_key(rpx, rpy, i)], 1);
}

// ---------------- kernel B: exclusive prefix scan, one pass ----------------
__global__ __launch_bounds__(SCANT) void scan_kernel(
    const int* __restrict__ counts, int* __restrict__ cursors)
{
    __shared__ int sm[SCANT];
    const int tid  = threadIdx.x;
    const int base = tid * SPT;

    int v[SPT];
    int run = 0;
    #pragma unroll
    for (int k = 0; k < SPT; ++k) {
        v[k] = run;                       // exclusive within thread
        run += counts[base + k];
    }
    sm[tid] = run;
    __syncthreads();
    #pragma unroll
    for (int off = 1; off < SCANT; off <<= 1) {
        int t = sm[tid];
        if (tid >= off) t += sm[tid - off];
        __syncthreads();
        sm[tid] = t;
        __syncthreads();
    }
    const int tbase = sm[tid] - run;      // exclusive prefix of thread totals
    #pragma unroll
    for (int k = 0; k < SPT; ++k)
        cursors[base + k] = tbase + v[k];
}

// ---------------- kernel C: scatter + weights (fused) ----------------
// Per point: find sorted position via cursor atomic, compute gaussian bin
// weights / clamped offsets, write packed 5x16B records at sorted position.
__global__ __launch_bounds__(TPB) void scatter_weights_kernel(
    const float* __restrict__ coords,
    const float* __restrict__ s_ptr,
    const float* __restrict__ offn,    // [NRES]
    const float* __restrict__ offi,    // [NHV]
    int* __restrict__ cursors,
    float4* __restrict__ w8a, float4* __restrict__ w8b,
    float4* __restrict__ wx4, int4* __restrict__ off4,
    float4* __restrict__ misc)
{
    const int i = blockIdx.x * TPB + threadIdx.x;   // i = b*NV + n

    const float2 cd = *(const float2*)(coords + (size_t)i * 2);
    const float px  = cd.y * (float)(NXV - 1);
    const float py  = cd.x * (float)(NYV - 1);
    const float rpx = rintf(px);          // round-half-even == jnp.round
    const float rpy = rintf(py);

    const int pos = atomicAdd(&cursors[bucket_key(rpx, rpy, i)], 1);

    const float s = s_ptr[0];
    const float k = -0.72134752044448169f / (s * s);  // -0.5*log2(e)/s^2
    // (1/(s*sqrt(2pi)) cancels in the w2d normalization)

    float wx[NHV], wy[NHV];
    float sx = 0.f, sy = 0.f;
    #pragma unroll
    for (int h = 0; h < NHV; ++h) {
        float ax = 0.f, ay = 0.f;
        #pragma unroll 6
        for (int t = 0; t < NRES / NHV; ++t) {
            const float off = offn[h * (NRES / NHV) + t];
            const float vx = fminf(fmaxf(rpx - off, 0.f), (float)NXV);
            const float vy = fminf(fmaxf(rpy - off, 0.f), (float)NXV);
            const float dx = vx - px;
            const float dy = vy - py;
            ax += EXP2(k * dx * dx);
            ay += EXP2(k * dy * dy);
        }
        wx[h] = ax; wy[h] = ay;
        sx += ax;  sy += ay;
    }
    const float inv = 1.0f / (sx * sy);   // w2d.sum() == (sum wx)*(sum wy)

    int ix[NHV], iy[NHV];
    #pragma unroll
    for (int h = 0; h < NHV; ++h) {
        const float fo = offi[h];
        ix[h] = (int)fminf(fmaxf(rintf(rpx - fo), 0.f), (float)(NXV - 1));
        iy[h] = (int)fminf(fmaxf(rintf(rpy - fo), 0.f), (float)(NXV - 1));
    }

    // column base aligned to float4; all 5 clamped cols live in [a, a+8)
    const int a = min(iy[NHV - 1] & ~3, NYV - 8);

    // scatter wy*inv into 8 slots (clamp duplicates accumulate)
    float w8[8];
    #pragma unroll
    for (int kk = 0; kk < 8; ++kk) {
        float w = 0.f;
        #pragma unroll
        for (int j = 0; j < NHV; ++j)
            w += (iy[j] - a == kk) ? wy[j] * inv : 0.f;
        w8[kk] = w;
    }

    w8a[pos] = make_float4(w8[0], w8[1], w8[2], w8[3]);
    w8b[pos] = make_float4(w8[4], w8[5], w8[6], w8[7]);
    wx4[pos] = make_float4(wx[0], wx[1], wx[2], wx[3]);
    off4[pos] = make_int4((ix[0] * NYV + a) * 4, (ix[1] * NYV + a) * 4,
                          (ix[2] * NYV + a) * 4, (ix[3] * NYV + a) * 4);
    misc[pos] = make_float4(wx[4], __int_as_float((ix[4] * NYV + a) * 4),
                            __int_as_float(i), 0.f);
}

// ---------------- kernel G: vectorized weighted gather, CPERT channels ----------------
__global__ __launch_bounds__(TPB, 4) void gather_kernel(
    const float* __restrict__ x,
    const float4* __restrict__ w8a, const float4* __restrict__ w8b,
    const float4* __restrict__ wx4, const int4* __restrict__ off4,
    const float4* __restrict__ misc,
    float* __restrict__ out)
{
    // XCD-chunk swizzle on point-chunk dimension
    const int nwg = NPTS / TPB;                       // 512
    const int bid = blockIdx.x;
    const int swz = (bid & 7) * (nwg / 8) + (bid >> 3);
    const int p   = swz * TPB + threadIdx.x;
    const int c0  = blockIdx.y * CPERT;

    const float4 wa = w8a[p];
    const float4 wb = w8b[p];
    const float4 wr = wx4[p];
    const int4   o4 = off4[p];
    const float4 ms = misc[p];
    const float  we = ms.x;
    const int    oe = __float_as_int(ms.y);
    const int    i  = __float_as_int(ms.z);
    const int    b  = i >> 14;
    const int    n  = i & (NV - 1);

    const int   ro[NHV] = {o4.x, o4.y, o4.z, o4.w, oe};
    const float rw[NHV] = {wr.x, wr.y, wr.z, wr.w, we};

    const char* base = (const char*)x + ((size_t)(b * CV + c0) << 20); // plane=1MB
    float acc[CPERT];
    #pragma unroll
    for (int q = 0; q < CPERT; ++q) acc[q] = 0.f;

    #pragma unroll
    for (int q = 0; q < CPERT; ++q) {
        const char* bq = base + ((size_t)q << 20);
        #pragma unroll
        for (int r = 0; r < NHV; ++r) {
            const float4* rp = (const float4*)(bq + (size_t)(unsigned)ro[r]);
            const float4 va = rp[0];
            const float4 vb = rp[1];
            const float rs = va.x * wa.x + va.y * wa.y + va.z * wa.z +
                             va.w * wa.w + vb.x * wb.x + vb.y * wb.y +
                             vb.z * wb.z + vb.w * wb.w;
            acc[q] = fmaf(rw[r], rs, acc[q]);
        }
    }

    #pragma unroll
    for (int q = 0; q < CPERT; ++q)
        out[(((size_t)(b * CV + c0 + q)) << 14) + n] = acc[q];
}

extern "C" void kernel_launch(void* const* d_in, const int* in_sizes, int n_in,
                              void* d_out, int out_size, void* d_ws, size_t ws_size,
                              hipStream_t stream) {
    const float* x      = (const float*)d_in[0];
    const float* coords = (const float*)d_in[1];
    const float* s_ptr  = (const float*)d_in[2];
    const float* offn   = (const float*)d_in[3];
    const float* offi   = (const float*)d_in[4];
    float* out = (float*)d_out;

    // workspace layout (16B-aligned arrays first); total ~10.5 MB
    char* w = (char*)d_ws;
    float4* w8a  = (float4*)w;  w += (size_t)NPTS * 16;
    float4* w8b  = (float4*)w;  w += (size_t)NPTS * 16;
    float4* wx4  = (float4*)w;  w += (size_t)NPTS * 16;
    int4*   off4 = (int4*)w;    w += (size_t)NPTS * 16;
    float4* misc = (float4*)w;  w += (size_t)NPTS * 16;
    int*    counts  = (int*)w;  w += (size_t)NBUCK * 4;
    int*    cursors = (int*)w;

    zero_counts_kernel<<<dim3(NBUCK / TPB), dim3(TPB), 0, stream>>>(counts);
    bucket_count_kernel<<<dim3(NPTS / TPB), dim3(TPB), 0, stream>>>(coords, counts);
    scan_kernel<<<dim3(1), dim3(SCANT), 0, stream>>>(counts, cursors);
    scatter_weights_kernel<<<dim3(NPTS / TPB), dim3(TPB), 0, stream>>>(
        coords, s_ptr, offn, offi, cursors, w8a, w8b, wx4, off4, misc);

    dim3 grid(NPTS / TPB, CV / CPERT, 1);
    gather_kernel<<<grid, dim3(TPB), 0, stream>>>(
        x, w8a, w8b, wx4, off4, misc, out);
}

// Round 5
// 262.169 us; speedup vs baseline: 1.0982x; 1.0982x over previous
//
#include <hip/hip_runtime.h>

// Problem constants (match reference)
#define BV    8
#define CV    16
#define NXV   512
#define NYV   512
#define NV    16384
#define NRES  90
#define NHV   5
#define TPB   256

#define NPTS  (BV * NV)             // 131072 points
#define TSH   5                     // 32x32-pixel tiles
#define TDIM  (NXV >> TSH)          // 16 tiles per axis
#define NBUCKB (TDIM * TDIM)        // 256 buckets per batch
#define NBUCK  (BV * NBUCKB)        // 2048 buckets total
#define SCANT 1024
#define SPT   (NBUCK / SCANT)       // 2

#define CPG   4                     // channels per gather workgroup
#define RROWS 36                    // staged rows  [r0-2, r0+34)
#define RCOLS 48                    // staged cols  [c0-8, c0+40)
#define RSEG  (RCOLS / 4)           // 12 float4 per row
#define SLOTS_PER_CH (RROWS * RSEG) // 432
#define SLOTS (CPG * SLOTS_PER_CH)  // 1728 float4 = 27648 B LDS

#if __has_builtin(__builtin_amdgcn_exp2f)
#define EXP2 __builtin_amdgcn_exp2f
#else
#define EXP2 exp2f
#endif

// ---------------- kernel Z: zero bucket counts ----------------
__global__ void zero_counts_kernel(int* __restrict__ counts) {
    int i = blockIdx.x * blockDim.x + threadIdx.x;
    if (i < NBUCK) counts[i] = 0;
}

__device__ __forceinline__ int bucket_key(float rpx, float rpy, int i) {
    const int tr = ((int)rpx) >> TSH;   // row-tile 0..15
    const int tc = ((int)rpy) >> TSH;   // col-tile 0..15
    return (i >> 14) * NBUCKB + tr * TDIM + tc;
}

// ---------------- kernel A: histogram ----------------
__global__ __launch_bounds__(TPB) void bucket_count_kernel(
    const float* __restrict__ coords, int* __restrict__ counts)
{
    const int i = blockIdx.x * TPB + threadIdx.x;   // i = b*NV + n
    const float2 cd = *(const float2*)(coords + (size_t)i * 2);
    const float rpx = rintf(cd.y * (float)(NXV - 1));
    const float rpy = rintf(cd.x * (float)(NYV - 1));
    atomicAdd(&counts[bucket_key(rpx, rpy, i)], 1);
}

// ---------------- kernel B: exclusive scan -> starts, cursors ----------------
__global__ __launch_bounds__(SCANT) void scan_kernel(
    const int* __restrict__ counts, int* __restrict__ starts,
    int* __restrict__ cursors)
{
    __shared__ int sm[SCANT];
    const int tid  = threadIdx.x;
    const int base = tid * SPT;

    int v[SPT];
    int run = 0;
    #pragma unroll
    for (int k = 0; k < SPT; ++k) {
        v[k] = run;                       // exclusive within thread
        run += counts[base + k];
    }
    sm[tid] = run;
    __syncthreads();
    #pragma unroll
    for (int off = 1; off < SCANT; off <<= 1) {
        int t = sm[tid];
        if (tid >= off) t += sm[tid - off];
        __syncthreads();
        sm[tid] = t;
        __syncthreads();
    }
    const int tbase = sm[tid] - run;      // exclusive prefix of thread totals
    #pragma unroll
    for (int k = 0; k < SPT; ++k) {
        const int e = tbase + v[k];
        starts[base + k]  = e;
        cursors[base + k] = e;
    }
}

// ---------------- kernel C: scatter + weights (fused) ----------------
__global__ __launch_bounds__(TPB) void scatter_weights_kernel(
    const float* __restrict__ coords,
    const float* __restrict__ s_ptr,
    const float* __restrict__ offn,    // [NRES]
    const float* __restrict__ offi,    // [NHV]
    int* __restrict__ cursors,
    float4* __restrict__ w8a, float4* __restrict__ w8b,
    float4* __restrict__ wx4, int4* __restrict__ off4,
    float4* __restrict__ misc)
{
    const int i = blockIdx.x * TPB + threadIdx.x;   // i = b*NV + n

    const float2 cd = *(const float2*)(coords + (size_t)i * 2);
    const float px  = cd.y * (float)(NXV - 1);
    const float py  = cd.x * (float)(NYV - 1);
    const float rpx = rintf(px);          // round-half-even == jnp.round
    const float rpy = rintf(py);

    const int pos = atomicAdd(&cursors[bucket_key(rpx, rpy, i)], 1);

    const float s = s_ptr[0];
    const float k = -0.72134752044448169f / (s * s);  // -0.5*log2(e)/s^2
    // (1/(s*sqrt(2pi)) cancels in the w2d normalization)

    float wx[NHV], wy[NHV];
    float sx = 0.f, sy = 0.f;
    #pragma unroll
    for (int h = 0; h < NHV; ++h) {
        float ax = 0.f, ay = 0.f;
        #pragma unroll 6
        for (int t = 0; t < NRES / NHV; ++t) {
            const float off = offn[h * (NRES / NHV) + t];
            const float vx = fminf(fmaxf(rpx - off, 0.f), (float)NXV);
            const float vy = fminf(fmaxf(rpy - off, 0.f), (float)NXV);
            const float dx = vx - px;
            const float dy = vy - py;
            ax += EXP2(k * dx * dx);
            ay += EXP2(k * dy * dy);
        }
        wx[h] = ax; wy[h] = ay;
        sx += ax;  sy += ay;
    }
    const float inv = 1.0f / (sx * sy);   // w2d.sum() == (sum wx)*(sum wy)

    int ix[NHV], iy[NHV];
    #pragma unroll
    for (int h = 0; h < NHV; ++h) {
        const float fo = offi[h];
        ix[h] = (int)fminf(fmaxf(rintf(rpx - fo), 0.f), (float)(NXV - 1));
        iy[h] = (int)fminf(fmaxf(rintf(rpy - fo), 0.f), (float)(NXV - 1));
    }

    // column base aligned to float4; all 5 clamped cols live in [a, a+8)
    const int a = min(iy[NHV - 1] & ~3, NYV - 8);

    // scatter wy*inv into 8 slots (clamp duplicates accumulate)
    float w8[8];
    #pragma unroll
    for (int kk = 0; kk < 8; ++kk) {
        float w = 0.f;
        #pragma unroll
        for (int j = 0; j < NHV; ++j)
            w += (iy[j] - a == kk) ? wy[j] * inv : 0.f;
        w8[kk] = w;
    }

    w8a[pos] = make_float4(w8[0], w8[1], w8[2], w8[3]);
    w8b[pos] = make_float4(w8[4], w8[5], w8[6], w8[7]);
    wx4[pos] = make_float4(wx[0], wx[1], wx[2], wx[3]);
    off4[pos] = make_int4((ix[0] * NYV + a) * 4, (ix[1] * NYV + a) * 4,
                          (ix[2] * NYV + a) * 4, (ix[3] * NYV + a) * 4);
    misc[pos] = make_float4(wx[4], __int_as_float((ix[4] * NYV + a) * 4),
                            __int_as_float(i), 0.f);
}

// ---------------- kernel G: tile-centric LDS gather ----------------
// One WG per (tile, 4-channel group). Stage 36x48 halo region x 4 channels
// into LDS (dense, coalesced), then each point-channel item reads 5 rows x
// 2 float4 from LDS.
__global__ __launch_bounds__(TPB) void tile_gather_kernel(
    const float* __restrict__ x,
    const int* __restrict__ starts, const int* __restrict__ ends,
    const float4* __restrict__ w8a, const float4* __restrict__ w8b,
    const float4* __restrict__ wx4, const int4* __restrict__ off4,
    const float4* __restrict__ misc,
    float* __restrict__ out)
{
    __shared__ float4 lds[SLOTS];          // 27648 B

    const int bid = blockIdx.x;            // b*256 + tr*16 + tc
    const int cg  = blockIdx.y;            // channel group (0..3)
    const int b   = bid >> 8;
    const int tr  = (bid >> 4) & (TDIM - 1);
    const int tc  = bid & (TDIM - 1);
    const int r0  = tr << TSH, c0 = tc << TSH;
    const int R0  = min(max(r0 - 2, 0), NXV - RROWS);
    const int W0  = min(max(c0 - 8, 0), NYV - RCOLS);

    const int tid = threadIdx.x;
    const char* bx = (const char*)x + ((size_t)(b * CV + cg * CPG) << 20);

    // ---- stage region into LDS (7 rounds of 256 float4 slots) ----
    #pragma unroll
    for (int kk = 0; kk < (SLOTS + TPB - 1) / TPB; ++kk) {
        const int sslot = tid + kk * TPB;
        if (sslot < SLOTS) {
            const int ch  = sslot / SLOTS_PER_CH;
            const int rem = sslot - ch * SLOTS_PER_CH;
            const int row = rem / RSEG;
            const int seg = rem - row * RSEG;
            lds[sslot] = *(const float4*)(bx + ((size_t)ch << 20)
                          + ((size_t)(R0 + row) << 11) + (W0 << 2) + (seg << 4));
        }
    }
    __syncthreads();

    // ---- process this bucket's points x CPG channels ----
    const int s0    = starts[bid];
    const int total = (ends[bid] - s0) << 2;   // cnt * CPG
    const char* ldsb = (const char*)lds;

    for (int item = tid; item < total; item += TPB) {
        const int p  = s0 + (item >> 2);
        const int ch = item & (CPG - 1);

        const float4 wa = w8a[p];
        const float4 wb = w8b[p];
        const float4 wr = wx4[p];
        const int4   o4 = off4[p];
        const float4 ms = misc[p];
        const float  we = ms.x;
        const int    oe = __float_as_int(ms.y);
        const int    i  = __float_as_int(ms.z);
        const int    n  = i & (NV - 1);

        // absolute plane byte-offset -> LDS byte-offset
        const int basech = ch * (SLOTS_PER_CH * 16) - R0 * (RCOLS * 4) - (W0 << 2);

        float acc = 0.f;
#define ROW(OFF, WROW) {                                                     \
        const int lo = basech + ((OFF) >> 11) * (RCOLS * 4) + ((OFF) & 2047);\
        const float4 va = *(const float4*)(ldsb + lo);                       \
        const float4 vb = *(const float4*)(ldsb + lo + 16);                  \
        const float rs = va.x * wa.x + va.y * wa.y + va.z * wa.z +           \
                         va.w * wa.w + vb.x * wb.x + vb.y * wb.y +           \
                         vb.z * wb.z + vb.w * wb.w;                          \
        acc = fmaf(WROW, rs, acc); }

        ROW(o4.x, wr.x)
        ROW(o4.y, wr.y)
        ROW(o4.z, wr.z)
        ROW(o4.w, wr.w)
        ROW(oe,   we)
#undef ROW

        out[(((size_t)(b * CV + cg * CPG + ch)) << 14) + n] = acc;
    }
}

extern "C" void kernel_launch(void* const* d_in, const int* in_sizes, int n_in,
                              void* d_out, int out_size, void* d_ws, size_t ws_size,
                              hipStream_t stream) {
    const float* x      = (const float*)d_in[0];
    const float* coords = (const float*)d_in[1];
    const float* s_ptr  = (const float*)d_in[2];
    const float* offn   = (const float*)d_in[3];
    const float* offi   = (const float*)d_in[4];
    float* out = (float*)d_out;

    // workspace layout (16B-aligned arrays first); ~10.5 MB
    char* w = (char*)d_ws;
    float4* w8a  = (float4*)w;  w += (size_t)NPTS * 16;
    float4* w8b  = (float4*)w;  w += (size_t)NPTS * 16;
    float4* wx4  = (float4*)w;  w += (size_t)NPTS * 16;
    int4*   off4 = (int4*)w;    w += (size_t)NPTS * 16;
    float4* misc = (float4*)w;  w += (size_t)NPTS * 16;
    int*    counts  = (int*)w;  w += (size_t)NBUCK * 4;
    int*    starts  = (int*)w;  w += (size_t)NBUCK * 4;
    int*    cursors = (int*)w;

    zero_counts_kernel<<<dim3(NBUCK / TPB), dim3(TPB), 0, stream>>>(counts);
    bucket_count_kernel<<<dim3(NPTS / TPB), dim3(TPB), 0, stream>>>(coords, counts);
    scan_kernel<<<dim3(1), dim3(SCANT), 0, stream>>>(counts, starts, cursors);
    scatter_weights_kernel<<<dim3(NPTS / TPB), dim3(TPB), 0, stream>>>(
        coords, s_ptr, offn, offi, cursors, w8a, w8b, wx4, off4, misc);

    dim3 grid(NBUCK, CV / CPG, 1);
    tile_gather_kernel<<<grid, dim3(TPB), 0, stream>>>(
        x, starts, cursors, w8a, w8b, wx4, off4, misc, out);
}